// Round 3
// baseline (76.335 us; speedup 1.0000x reference)
//
#include <hip/hip_runtime.h>
#include <hip/hip_bf16.h>

#define HM_W 512
#define HM_H 512
#define PW   508   // 512 - 5 + 1

__device__ __forceinline__ void load_row8(const float* __restrict__ hm, int y, int c0, float v[8]) {
    const float4* rp = reinterpret_cast<const float4*>(hm + y * HM_W + c0);
    float4 a = rp[0];
    float4 b = rp[1];
    v[0]=a.x; v[1]=a.y; v[2]=a.z; v[3]=a.w;
    v[4]=b.x; v[5]=b.y; v[6]=b.z; v[7]=b.w;
}

// Per-lane 5-wide window sums from per-lane colsums s[0..7] (cols lane*8..lane*8+7),
// cross-lane tail via shfl, then wave-wide argmax (tie-break lowest col).
// Whole wave must be active. All lanes end with the result.
__device__ __forceinline__ void row_best_shfl(const float s[8], int lane, float& bv, int& bc) {
    float cb[12];
#pragma unroll
    for (int j = 0; j < 8; ++j) cb[j] = s[j];
#pragma unroll
    for (int j = 0; j < 4; ++j) cb[8 + j] = __shfl_down(s[j], 1);
    bv = -__builtin_inff();
    bc = 0x7fffffff;
    int c0 = lane * 8;
#pragma unroll
    for (int j = 0; j < 8; ++j) {
        int c = c0 + j;
        float w = cb[j] + cb[j + 1] + cb[j + 2] + cb[j + 3] + cb[j + 4];
        if (c < PW && w > bv) { bv = w; bc = c; }   // ascending c keeps lowest col on tie
    }
#pragma unroll
    for (int m = 1; m < 64; m <<= 1) {
        float ov = __shfl_xor(bv, m);
        int   oc = __shfl_xor(bc, m);
        if (ov > bv || (ov == bv && oc < bc)) { bv = ov; bc = oc; }
    }
}

// Phase 1: per-row argmax of the 5x5 box-sum, rolling 5-row register window.
// Each wave produces 32 aggregate rows from 36 input-row loads (1.125x redundancy).
// grid = (4, 128), block = 256 (4 waves). No LDS, no barriers.
__global__ void phase1_kernel(const float* __restrict__ hm_all,
                              float* __restrict__ rowv_ws, int* __restrict__ rowc_ws) {
    int b = blockIdx.y;
    int wave = threadIdx.x >> 6;
    int lane = threadIdx.x & 63;
    int c0 = lane * 8;
    const float* hm = hm_all + (size_t)b * HM_W * HM_H;

    int rbase = (blockIdx.x * 4 + wave) * 32;
    if (rbase >= PW) return;

    float w0[8], w1[8], w2[8], w3[8], w4[8];
    load_row8(hm, rbase + 0, c0, w0);
    load_row8(hm, rbase + 1, c0, w1);
    load_row8(hm, rbase + 2, c0, w2);
    load_row8(hm, rbase + 3, c0, w3);

#pragma unroll
    for (int rr = 0; rr < 32; ++rr) {
        int y = rbase + rr;
        if (y >= PW) break;                 // wave-uniform
        load_row8(hm, y + 4, c0, w4);
        float s[8];
#pragma unroll
        for (int j = 0; j < 8; ++j)
            s[j] = ((((w0[j] + w1[j]) + w2[j]) + w3[j]) + w4[j]);
        float bv; int bc;
        row_best_shfl(s, lane, bv, bc);
        if (lane == 0) {
            rowv_ws[b * 512 + y] = bv;
            rowc_ws[b * 512 + y] = bc;
        }
#pragma unroll
        for (int j = 0; j < 8; ++j) { w0[j] = w1[j]; w1[j] = w2[j]; w2[j] = w3[j]; w3[j] = w4[j]; }
    }
}

// Phase 2: per batch, 6 sequential peak extractions. Row table lives entirely in
// registers (8 slots/lane, stride-64); only repaired entries broadcast via a tiny
// double-buffered LDS array. ONE __syncthreads per iteration.
// grid = 128, block = 576 (9 waves; wave w repairs row y0+w).
__global__ void __launch_bounds__(576) phase2_kernel(const float* __restrict__ hm_all,
                              const float* __restrict__ rowv_ws,
                              const int* __restrict__ rowc_ws,
                              int* __restrict__ out) {
    int b = blockIdx.x;
    const float* hm = hm_all + (size_t)b * HM_W * HM_H;
    int t = threadIdx.x;
    int wave = t >> 6, lane = t & 63;
    int c0 = lane * 8;

    __shared__ float updv[2][9];
    __shared__ int   updc[2][9];

    // Full per-row best table in registers: slot j holds row j*64+lane.
    float rv[8]; int rc[8];
#pragma unroll
    for (int j = 0; j < 8; ++j) {
        int idx = j * 64 + lane;
        if (idx < PW) { rv[j] = rowv_ws[b * 512 + idx]; rc[j] = rowc_ws[b * 512 + idx]; }
        else          { rv[j] = -__builtin_inff();      rc[j] = 0; }
    }

    int zrr[6], zcc[6];

#pragma unroll
    for (int it = 0; it < 6; ++it) {
        // ---- wave-wide argmax over register table (tie-break lowest row) ----
        float bv = rv[0]; int bi = lane; int bc = rc[0];
#pragma unroll
        for (int j = 1; j < 8; ++j) {
            if (rv[j] > bv) { bv = rv[j]; bi = j * 64 + lane; bc = rc[j]; }  // ascending row per lane
        }
#pragma unroll
        for (int m = 1; m < 64; m <<= 1) {
            float ov = __shfl_xor(bv, m);
            int   oi = __shfl_xor(bi, m);
            int   oc = __shfl_xor(bc, m);
            if (ov > bv || (ov == bv && oi < bi)) { bv = ov; bi = oi; bc = oc; }
        }
        int fr = bi, fc = bc;              // identical in every wave
        zrr[it] = fr; zcc[it] = fc;
        if (t == 0) {
            out[b * 12 + it * 2 + 0] = fc + 2;   // SWAP_RC: (c+R, r+R)
            out[b * 12 + it * 2 + 1] = fr + 2;
        }
        if (it == 5) break;                // compile-time: last peak needs no repair

        int y0 = fr - 4 < 0 ? 0 : fr - 4;
        int y1 = fr + 4 > PW - 1 ? PW - 1 : fr + 4;
        int buf = it & 1;

        // ---- repair: wave w recomputes row y0+w (loads issue immediately) ----
        int y = y0 + wave;                 // wave-uniform predicate
        if (y <= y1) {
            float s[8];
#pragma unroll
            for (int j = 0; j < 8; ++j) s[j] = 0.f;
#pragma unroll
            for (int i = 0; i < 5; ++i) {
                float v[8];
                load_row8(hm, y + i, c0, v);
#pragma unroll
                for (int j = 0; j < 8; ++j) {
                    float vv = v[j];
#pragma unroll
                    for (int k = 0; k < 6; ++k) {
                        if (k <= it && (unsigned)(y + i - zrr[k]) < 5u
                                    && (unsigned)(c0 + j - zcc[k]) < 5u)
                            vv = 0.f;
                    }
                    s[j] += vv;
                }
            }
            float nv; int nc;
            row_best_shfl(s, lane, nv, nc);
            if (lane == 0) { updv[buf][wave] = nv; updc[buf][wave] = nc; }
        }

        __syncthreads();   // the ONLY barrier: repair writes -> patch reads
                           // (WAR on buf is separated by the next iteration's barrier)

        // ---- patch register table with the <=9 updated rows ----
        int n = y1 - y0;                   // block-uniform
#pragma unroll
        for (int u = 0; u < 9; ++u) {
            if (u <= n) {
                float nv = updv[buf][u]; int ncol = updc[buf][u];
                int yy = y0 + u;
                int jj = yy >> 6, ll = yy & 63;
#pragma unroll
                for (int j = 0; j < 8; ++j)   // static reg indexing (rule #20)
                    if (j == jj && lane == ll) { rv[j] = nv; rc[j] = ncol; }
            }
        }
    }
}

extern "C" void kernel_launch(void* const* d_in, const int* in_sizes, int n_in,
                              void* d_out, int out_size, void* d_ws, size_t ws_size,
                              hipStream_t stream) {
    const float* hm = (const float*)d_in[0];
    int* out = (int*)d_out;
    float* rowv_ws = (float*)d_ws;
    int*   rowc_ws = (int*)((char*)d_ws + (size_t)128 * 512 * sizeof(float));

    phase1_kernel<<<dim3(4, 128), dim3(256), 0, stream>>>(hm, rowv_ws, rowc_ws);
    phase2_kernel<<<dim3(128), dim3(576), 0, stream>>>(hm, rowv_ws, rowc_ws, out);
}

// Round 4
// 66.478 us; speedup vs baseline: 1.1483x; 1.1483x over previous
//
#include <hip/hip_runtime.h>
#include <hip/hip_bf16.h>

#define HM_W 512
#define HM_H 512
#define PW   508   // 512 - 5 + 1

__device__ __forceinline__ void load_row8(const float* __restrict__ hm, int y, int c0, float v[8]) {
    const float4* rp = reinterpret_cast<const float4*>(hm + y * HM_W + c0);
    float4 a = rp[0];
    float4 b = rp[1];
    v[0]=a.x; v[1]=a.y; v[2]=a.z; v[3]=a.w;
    v[4]=b.x; v[5]=b.y; v[6]=b.z; v[7]=b.w;
}

// Per-lane 5-wide window sums from per-lane colsums s[0..7] (cols lane*8..lane*8+7),
// cross-lane tail via shfl, then wave-wide argmax (tie-break lowest col).
// Whole wave must be active. All lanes end with the result.
__device__ __forceinline__ void row_best_shfl(const float s[8], int lane, float& bv, int& bc) {
    float cb[12];
#pragma unroll
    for (int j = 0; j < 8; ++j) cb[j] = s[j];
#pragma unroll
    for (int j = 0; j < 4; ++j) cb[8 + j] = __shfl_down(s[j], 1);
    bv = -__builtin_inff();
    bc = 0x7fffffff;
    int c0 = lane * 8;
#pragma unroll
    for (int j = 0; j < 8; ++j) {
        int c = c0 + j;
        float w = cb[j] + cb[j + 1] + cb[j + 2] + cb[j + 3] + cb[j + 4];
        if (c < PW && w > bv) { bv = w; bc = c; }   // ascending c keeps lowest col on tie
    }
#pragma unroll
    for (int m = 1; m < 64; m <<= 1) {
        float ov = __shfl_xor(bv, m);
        int   oc = __shfl_xor(bc, m);
        if (ov > bv || (ov == bv && oc < bc)) { bv = ov; bc = oc; }
    }
}

// Phase 1 (round-2 exact): per-row argmax of the 5x5 box-sum, rolling 5-row
// register window. Each wave: 16 aggregate rows from 20 input-row loads.
// grid = (8, 128) = 1024 blocks (4 blocks/CU), block = 256 (4 waves).
__global__ void phase1_kernel(const float* __restrict__ hm_all,
                              float* __restrict__ rowv_ws, int* __restrict__ rowc_ws) {
    int b = blockIdx.y;
    int wave = threadIdx.x >> 6;
    int lane = threadIdx.x & 63;
    int c0 = lane * 8;
    const float* hm = hm_all + (size_t)b * HM_W * HM_H;

    int rbase = (blockIdx.x * 4 + wave) * 16;
    if (rbase >= PW) return;

    float w0[8], w1[8], w2[8], w3[8], w4[8];
    load_row8(hm, rbase + 0, c0, w0);
    load_row8(hm, rbase + 1, c0, w1);
    load_row8(hm, rbase + 2, c0, w2);
    load_row8(hm, rbase + 3, c0, w3);

#pragma unroll
    for (int rr = 0; rr < 16; ++rr) {
        int y = rbase + rr;
        if (y >= PW) break;                 // wave-uniform
        load_row8(hm, y + 4, c0, w4);
        float s[8];
#pragma unroll
        for (int j = 0; j < 8; ++j)
            s[j] = ((((w0[j] + w1[j]) + w2[j]) + w3[j]) + w4[j]);
        float bv; int bc;
        row_best_shfl(s, lane, bv, bc);
        if (lane == 0) {
            rowv_ws[b * 512 + y] = bv;
            rowc_ws[b * 512 + y] = bc;
        }
#pragma unroll
        for (int j = 0; j < 8; ++j) { w0[j] = w1[j]; w1[j] = w2[j]; w2[j] = w3[j]; w3[j] = w4[j]; }
    }
}

// Phase 2 (round-3 version, kept): per batch, 6 sequential peak extractions.
// Row table entirely in registers (8 slots/lane, stride-64); repaired entries
// broadcast via tiny double-buffered LDS. ONE __syncthreads per iteration.
// grid = 128, block = 576 (9 waves; wave w repairs row y0+w).
__global__ void __launch_bounds__(576) phase2_kernel(const float* __restrict__ hm_all,
                              const float* __restrict__ rowv_ws,
                              const int* __restrict__ rowc_ws,
                              int* __restrict__ out) {
    int b = blockIdx.x;
    const float* hm = hm_all + (size_t)b * HM_W * HM_H;
    int t = threadIdx.x;
    int wave = t >> 6, lane = t & 63;
    int c0 = lane * 8;

    __shared__ float updv[2][9];
    __shared__ int   updc[2][9];

    // Full per-row best table in registers: slot j holds row j*64+lane.
    float rv[8]; int rc[8];
#pragma unroll
    for (int j = 0; j < 8; ++j) {
        int idx = j * 64 + lane;
        if (idx < PW) { rv[j] = rowv_ws[b * 512 + idx]; rc[j] = rowc_ws[b * 512 + idx]; }
        else          { rv[j] = -__builtin_inff();      rc[j] = 0; }
    }

    int zrr[6], zcc[6];

#pragma unroll
    for (int it = 0; it < 6; ++it) {
        // ---- wave-wide argmax over register table (tie-break lowest row) ----
        float bv = rv[0]; int bi = lane; int bc = rc[0];
#pragma unroll
        for (int j = 1; j < 8; ++j) {
            if (rv[j] > bv) { bv = rv[j]; bi = j * 64 + lane; bc = rc[j]; }  // ascending row per lane
        }
#pragma unroll
        for (int m = 1; m < 64; m <<= 1) {
            float ov = __shfl_xor(bv, m);
            int   oi = __shfl_xor(bi, m);
            int   oc = __shfl_xor(bc, m);
            if (ov > bv || (ov == bv && oi < bi)) { bv = ov; bi = oi; bc = oc; }
        }
        int fr = bi, fc = bc;              // identical in every wave
        zrr[it] = fr; zcc[it] = fc;
        if (t == 0) {
            out[b * 12 + it * 2 + 0] = fc + 2;   // SWAP_RC: (c+R, r+R)
            out[b * 12 + it * 2 + 1] = fr + 2;
        }
        if (it == 5) break;                // compile-time: last peak needs no repair

        int y0 = fr - 4 < 0 ? 0 : fr - 4;
        int y1 = fr + 4 > PW - 1 ? PW - 1 : fr + 4;
        int buf = it & 1;

        // ---- repair: wave w recomputes row y0+w (loads issue immediately) ----
        int y = y0 + wave;                 // wave-uniform predicate
        if (y <= y1) {
            float s[8];
#pragma unroll
            for (int j = 0; j < 8; ++j) s[j] = 0.f;
#pragma unroll
            for (int i = 0; i < 5; ++i) {
                float v[8];
                load_row8(hm, y + i, c0, v);
#pragma unroll
                for (int j = 0; j < 8; ++j) {
                    float vv = v[j];
#pragma unroll
                    for (int k = 0; k < 6; ++k) {
                        if (k <= it && (unsigned)(y + i - zrr[k]) < 5u
                                    && (unsigned)(c0 + j - zcc[k]) < 5u)
                            vv = 0.f;
                    }
                    s[j] += vv;
                }
            }
            float nv; int nc;
            row_best_shfl(s, lane, nv, nc);
            if (lane == 0) { updv[buf][wave] = nv; updc[buf][wave] = nc; }
        }

        __syncthreads();   // the ONLY barrier: repair writes -> patch reads
                           // (WAR on buf separated by the next iteration's barrier)

        // ---- patch register table with the <=9 updated rows ----
        int n = y1 - y0;                   // block-uniform
#pragma unroll
        for (int u = 0; u < 9; ++u) {
            if (u <= n) {
                float nv = updv[buf][u]; int ncol = updc[buf][u];
                int yy = y0 + u;
                int jj = yy >> 6, ll = yy & 63;
#pragma unroll
                for (int j = 0; j < 8; ++j)   // static reg indexing (rule #20)
                    if (j == jj && lane == ll) { rv[j] = nv; rc[j] = ncol; }
            }
        }
    }
}

extern "C" void kernel_launch(void* const* d_in, const int* in_sizes, int n_in,
                              void* d_out, int out_size, void* d_ws, size_t ws_size,
                              hipStream_t stream) {
    const float* hm = (const float*)d_in[0];
    int* out = (int*)d_out;
    float* rowv_ws = (float*)d_ws;
    int*   rowc_ws = (int*)((char*)d_ws + (size_t)128 * 512 * sizeof(float));

    phase1_kernel<<<dim3(8, 128), dim3(256), 0, stream>>>(hm, rowv_ws, rowc_ws);
    phase2_kernel<<<dim3(128), dim3(576), 0, stream>>>(hm, rowv_ws, rowc_ws, out);
}

// Round 5
// 58.287 us; speedup vs baseline: 1.3096x; 1.1405x over previous
//
#include <hip/hip_runtime.h>
#include <hip/hip_bf16.h>

#define HM_W 512
#define HM_H 512
#define PW   508   // 512 - 5 + 1

__device__ __forceinline__ void load_row8(const float* __restrict__ hm, int y, int c0, float v[8]) {
    const float4* rp = reinterpret_cast<const float4*>(hm + y * HM_W + c0);
    float4 a = rp[0];
    float4 b = rp[1];
    v[0]=a.x; v[1]=a.y; v[2]=a.z; v[3]=a.w;
    v[4]=b.x; v[5]=b.y; v[6]=b.z; v[7]=b.w;
}

// Per-lane 5-wide window sums from per-lane colsums s[0..7] (cols lane*8..lane*8+7),
// cross-lane tail via shfl, then wave-wide argmax (tie-break lowest col).
// Whole wave must be active. All lanes end with the result.
__device__ __forceinline__ void row_best_shfl(const float s[8], int lane, float& bv, int& bc) {
    float cb[12];
#pragma unroll
    for (int j = 0; j < 8; ++j) cb[j] = s[j];
#pragma unroll
    for (int j = 0; j < 4; ++j) cb[8 + j] = __shfl_down(s[j], 1);
    bv = -__builtin_inff();
    bc = 0x7fffffff;
    int c0 = lane * 8;
#pragma unroll
    for (int j = 0; j < 8; ++j) {
        int c = c0 + j;
        float w = cb[j] + cb[j + 1] + cb[j + 2] + cb[j + 3] + cb[j + 4];
        if (c < PW && w > bv) { bv = w; bc = c; }   // ascending c keeps lowest col on tie
    }
#pragma unroll
    for (int m = 1; m < 64; m <<= 1) {
        float ov = __shfl_xor(bv, m);
        int   oc = __shfl_xor(bc, m);
        if (ov > bv || (ov == bv && oc < bc)) { bv = ov; bc = oc; }
    }
}

// Phase 1: per-row argmax of the 5x5 box-sum. Rolling 5-row register window with
// prefetch depth 2: the load issued at iteration rr is consumed at rr+2, so ~2
// iterations of VALU+DS work cover the HBM/L3 latency (plus 4 waves/SIMD TLP).
// Each wave: 16 aggregate rows from 22 row-loads. grid = (8,128), block = 256.
__global__ void phase1_kernel(const float* __restrict__ hm_all,
                              float* __restrict__ rowv_ws, int* __restrict__ rowc_ws) {
    int b = blockIdx.y;
    int wave = threadIdx.x >> 6;
    int lane = threadIdx.x & 63;
    int c0 = lane * 8;
    const float* hm = hm_all + (size_t)b * HM_W * HM_H;

    int rbase = (blockIdx.x * 4 + wave) * 16;
    if (rbase >= PW) return;

    float w0[8], w1[8], w2[8], w3[8], n0[8], n1[8];
    load_row8(hm, rbase + 0, c0, w0);
    load_row8(hm, rbase + 1, c0, w1);
    load_row8(hm, rbase + 2, c0, w2);
    load_row8(hm, rbase + 3, c0, w3);
    load_row8(hm, rbase + 4, c0, n0);   // 5th row of iteration 0
    load_row8(hm, rbase + 5, c0, n1);   // 5th row of iteration 1

#pragma unroll
    for (int rr = 0; rr < 16; ++rr) {
        int y = rbase + rr;
        if (y >= PW) break;                 // wave-uniform
        // Prefetch the 5th row of iteration rr+2. Clamped rows are only shifted
        // into slots consumed by iterations that don't execute (y+2 > PW-1).
        float n2[8];
        int yp = y + 6; yp = yp > (HM_H - 1) ? (HM_H - 1) : yp;
        load_row8(hm, yp, c0, n2);

        float s[8];
#pragma unroll
        for (int j = 0; j < 8; ++j)
            s[j] = ((((w0[j] + w1[j]) + w2[j]) + w3[j]) + n0[j]);   // same order as before
        float bv; int bc;
        row_best_shfl(s, lane, bv, bc);
        if (lane == 0) {
            rowv_ws[b * 512 + y] = bv;
            rowc_ws[b * 512 + y] = bc;
        }
#pragma unroll
        for (int j = 0; j < 8; ++j) {
            w0[j] = w1[j]; w1[j] = w2[j]; w2[j] = w3[j];
            w3[j] = n0[j]; n0[j] = n1[j]; n1[j] = n2[j];
        }
    }
}

// Phase 2 (round-2 exact, known-good): per batch, 6 sequential peak extractions
// with single-step parallel row repair. grid = 128, block = 1024 (16 waves).
__global__ void __launch_bounds__(1024) phase2_kernel(const float* __restrict__ hm_all,
                              const float* __restrict__ rowv_ws,
                              const int* __restrict__ rowc_ws,
                              int* __restrict__ out) {
    int b = blockIdx.x;
    const float* hm = hm_all + (size_t)b * HM_W * HM_H;
    int t = threadIdx.x;
    int wave = t >> 6, lane = t & 63;
    int c0 = lane * 8;

    __shared__ float rowv[512];
    __shared__ int   rowc[512];

    if (t < 512) {
        if (t < PW) { rowv[t] = rowv_ws[b * 512 + t]; rowc[t] = rowc_ws[b * 512 + t]; }
        else        { rowv[t] = -__builtin_inff();    rowc[t] = 0; }
    }

    int zrr[6], zcc[6];

#pragma unroll
    for (int it = 0; it < 6; ++it) {
        __syncthreads();   // (A) rowv/rowc stable from previous iteration's writes

        // ---- every wave redundantly computes the block argmax (tie: lowest row) ----
        float bv = -__builtin_inff(); int bi = 0x7fffffff;
#pragma unroll
        for (int j = 0; j < 8; ++j) {
            int idx = j * 64 + lane;       // stride-64: conflict-free, ascending idx per lane
            float v = rowv[idx];
            if (v > bv) { bv = v; bi = idx; }
        }
#pragma unroll
        for (int m = 1; m < 64; m <<= 1) {
            float ov = __shfl_xor(bv, m);
            int   oi = __shfl_xor(bi, m);
            if (ov > bv || (ov == bv && oi < bi)) { bv = ov; bi = oi; }
        }
        int fr = bi;
        int fc = rowc[fr];                 // same addr across lanes: broadcast
        zrr[it] = fr; zcc[it] = fc;        // kept in registers by every thread
        if (t == 0) {
            out[b * 12 + it * 2 + 0] = fc + 2;   // SWAP_RC: (c+R, r+R)
            out[b * 12 + it * 2 + 1] = fr + 2;
        }
        if (it == 5) break;                // last peak: no repair needed (compile-time)

        __syncthreads();   // (B) all argmax reads done before repair writes

        // ---- repair the <=9 affected rows, one wave each, in parallel ----
        int y0 = fr - 4 < 0 ? 0 : fr - 4;
        int y1 = fr + 4 > PW - 1 ? PW - 1 : fr + 4;
        int y  = y0 + wave;                // wave-uniform condition below
        if (wave < 9 && y <= y1) {
            float s[8];
#pragma unroll
            for (int j = 0; j < 8; ++j) s[j] = 0.f;
#pragma unroll
            for (int i = 0; i < 5; ++i) {
                float v[8];
                load_row8(hm, y + i, c0, v);
#pragma unroll
                for (int j = 0; j < 8; ++j) {
                    float vv = v[j];
#pragma unroll
                    for (int k = 0; k < 6; ++k) {
                        if (k <= it && (unsigned)(y + i - zrr[k]) < 5u
                                    && (unsigned)(c0 + j - zcc[k]) < 5u)
                            vv = 0.f;
                    }
                    s[j] += vv;
                }
            }
            float nv; int nc;
            row_best_shfl(s, lane, nv, nc);
            if (lane == 0) { rowv[y] = nv; rowc[y] = nc; }
        }
    }
}

extern "C" void kernel_launch(void* const* d_in, const int* in_sizes, int n_in,
                              void* d_out, int out_size, void* d_ws, size_t ws_size,
                              hipStream_t stream) {
    const float* hm = (const float*)d_in[0];
    int* out = (int*)d_out;
    float* rowv_ws = (float*)d_ws;
    int*   rowc_ws = (int*)((char*)d_ws + (size_t)128 * 512 * sizeof(float));

    phase1_kernel<<<dim3(8, 128), dim3(256), 0, stream>>>(hm, rowv_ws, rowc_ws);
    phase2_kernel<<<dim3(128), dim3(1024), 0, stream>>>(hm, rowv_ws, rowc_ws, out);
}

// Round 6
// 53.299 us; speedup vs baseline: 1.4322x; 1.0936x over previous
//
#include <hip/hip_runtime.h>
#include <hip/hip_bf16.h>

#define HM_W 512
#define HM_H 512
#define PW   508   // 512 - 5 + 1

__device__ __forceinline__ void load_row8(const float* __restrict__ hm, int y, int c0, float v[8]) {
    const float4* rp = reinterpret_cast<const float4*>(hm + y * HM_W + c0);
    float4 a = rp[0];
    float4 b = rp[1];
    v[0]=a.x; v[1]=a.y; v[2]=a.z; v[3]=a.w;
    v[4]=b.x; v[5]=b.y; v[6]=b.z; v[7]=b.w;
}

// Per-lane 5-wide window sums from per-lane colsums s[0..7] (cols lane*8..lane*8+7),
// cross-lane tail via shfl, then wave-wide argmax (tie-break lowest col).
// Whole wave must be active. All lanes end with the result.
__device__ __forceinline__ void row_best_shfl(const float s[8], int lane, float& bv, int& bc) {
    float cb[12];
#pragma unroll
    for (int j = 0; j < 8; ++j) cb[j] = s[j];
#pragma unroll
    for (int j = 0; j < 4; ++j) cb[8 + j] = __shfl_down(s[j], 1);
    bv = -__builtin_inff();
    bc = 0x7fffffff;
    int c0 = lane * 8;
#pragma unroll
    for (int j = 0; j < 8; ++j) {
        int c = c0 + j;
        float w = cb[j] + cb[j + 1] + cb[j + 2] + cb[j + 3] + cb[j + 4];
        if (c < PW && w > bv) { bv = w; bc = c; }   // ascending c keeps lowest col on tie
    }
#pragma unroll
    for (int m = 1; m < 64; m <<= 1) {
        float ov = __shfl_xor(bv, m);
        int   oc = __shfl_xor(bc, m);
        if (ov > bv || (ov == bv && oc < bc)) { bv = ov; bc = oc; }
    }
}

// Phase 1 (round-2 exact, best known): rolling 5-row register window,
// 16 aggregate rows per wave from 20 row-loads. grid = (8,128), block = 256.
__global__ void phase1_kernel(const float* __restrict__ hm_all,
                              float* __restrict__ rowv_ws, int* __restrict__ rowc_ws) {
    int b = blockIdx.y;
    int wave = threadIdx.x >> 6;
    int lane = threadIdx.x & 63;
    int c0 = lane * 8;
    const float* hm = hm_all + (size_t)b * HM_W * HM_H;

    int rbase = (blockIdx.x * 4 + wave) * 16;
    if (rbase >= PW) return;

    float w0[8], w1[8], w2[8], w3[8], w4[8];
    load_row8(hm, rbase + 0, c0, w0);
    load_row8(hm, rbase + 1, c0, w1);
    load_row8(hm, rbase + 2, c0, w2);
    load_row8(hm, rbase + 3, c0, w3);

#pragma unroll
    for (int rr = 0; rr < 16; ++rr) {
        int y = rbase + rr;
        if (y >= PW) break;                 // wave-uniform
        load_row8(hm, y + 4, c0, w4);
        float s[8];
#pragma unroll
        for (int j = 0; j < 8; ++j)
            s[j] = ((((w0[j] + w1[j]) + w2[j]) + w3[j]) + w4[j]);
        float bv; int bc;
        row_best_shfl(s, lane, bv, bc);
        if (lane == 0) {
            rowv_ws[b * 512 + y] = bv;
            rowc_ws[b * 512 + y] = bc;
        }
#pragma unroll
        for (int j = 0; j < 8; ++j) { w0[j] = w1[j]; w1[j] = w2[j]; w2[j] = w3[j]; w3[j] = w4[j]; }
    }
}

// Phase 2: LDS row table + ONE barrier per iteration. Repairs write a tiny
// double-buffered side buffer; next iteration's argmax overrides stale rowv
// entries from it while 9 threads patch rowv in place (race-benign: readers
// discard any racy read via the override; writes carry the identical value).
// grid = 128, block = 640 (10 waves; waves 0..8 repair rows y0..y0+8).
__global__ void __launch_bounds__(640) phase2_kernel(const float* __restrict__ hm_all,
                              const float* __restrict__ rowv_ws,
                              const int* __restrict__ rowc_ws,
                              int* __restrict__ out) {
    int b = blockIdx.x;
    const float* hm = hm_all + (size_t)b * HM_W * HM_H;
    int t = threadIdx.x;
    int wave = t >> 6, lane = t & 63;
    int c0 = lane * 8;

    __shared__ float rowv[512];
    __shared__ int   rowc[512];
    __shared__ float updv[2][9];
    __shared__ int   updc[2][9];
    __shared__ int   upd_y0[2];
    __shared__ int   upd_n[2];

    if (t < 512) {
        if (t < PW) { rowv[t] = rowv_ws[b * 512 + t]; rowc[t] = rowc_ws[b * 512 + t]; }
        else        { rowv[t] = -__builtin_inff();    rowc[t] = 0; }
    }
    if (t == 0) { upd_y0[1] = -1000; upd_n[1] = 0; }   // it=0 reads pbuf=1: empty

    int zrr[6], zcc[6];

#pragma unroll
    for (int it = 0; it < 6; ++it) {
        __syncthreads();   // the ONLY barrier: prev repair writes -> this iter's reads

        int pbuf = (it + 1) & 1;           // buffer written by previous iteration
        int py0 = upd_y0[pbuf];            // block-uniform
        int pn  = upd_n[pbuf];

        // ---- per-thread argmax over 8 stride-64 entries, overriding stale rows ----
        float bv = -__builtin_inff(); int bi = 0x7fffffff;
#pragma unroll
        for (int j = 0; j < 8; ++j) {
            int idx = j * 64 + lane;
            float v = rowv[idx];
            unsigned u = (unsigned)(idx - py0);
            if (u < (unsigned)pn) v = updv[pbuf][u];
            if (v > bv) { bv = v; bi = idx; }   // ascending idx keeps lowest row on tie
        }
#pragma unroll
        for (int m = 1; m < 64; m <<= 1) {
            float ov = __shfl_xor(bv, m);
            int   oi = __shfl_xor(bi, m);
            if (ov > bv || (ov == bv && oi < bi)) { bv = ov; bi = oi; }
        }
        int fr = bi;
        unsigned uf = (unsigned)(fr - py0);
        int fc = (uf < (unsigned)pn) ? updc[pbuf][uf] : rowc[fr];   // LDS broadcast
        zrr[it] = fr; zcc[it] = fc;
        if (t == 0) {
            out[b * 12 + it * 2 + 0] = fc + 2;   // SWAP_RC: (c+R, r+R)
            out[b * 12 + it * 2 + 1] = fr + 2;
        }

        // ---- patch rowv/rowc with the previous iteration's repairs ----
        // Concurrent with the reads above, but race-benign (see header comment).
        if (t < 9 && t < pn) {
            int yy = py0 + t;
            rowv[yy] = updv[pbuf][t];
            rowc[yy] = updc[pbuf][t];
        }

        if (it == 5) break;                // compile-time: last peak needs no repair

        // ---- repair the <=9 affected rows, one wave each; loads issue now ----
        int y0 = fr - 4 < 0 ? 0 : fr - 4;
        int y1 = fr + 4 > PW - 1 ? PW - 1 : fr + 4;
        int buf = it & 1;
        int y = y0 + wave;                 // wave-uniform predicate
        if (wave < 9 && y <= y1) {
            float s[8];
#pragma unroll
            for (int j = 0; j < 8; ++j) s[j] = 0.f;
#pragma unroll
            for (int i = 0; i < 5; ++i) {
                float v[8];
                load_row8(hm, y + i, c0, v);
#pragma unroll
                for (int j = 0; j < 8; ++j) {
                    float vv = v[j];
#pragma unroll
                    for (int k = 0; k < 6; ++k) {
                        if (k <= it && (unsigned)(y + i - zrr[k]) < 5u
                                    && (unsigned)(c0 + j - zcc[k]) < 5u)
                            vv = 0.f;
                    }
                    s[j] += vv;
                }
            }
            float nv; int nc;
            row_best_shfl(s, lane, nv, nc);
            if (lane == 0) { updv[buf][wave] = nv; updc[buf][wave] = nc; }
        }
        if (t == 0) { upd_y0[buf] = y0; upd_n[buf] = y1 - y0 + 1; }
    }
}

extern "C" void kernel_launch(void* const* d_in, const int* in_sizes, int n_in,
                              void* d_out, int out_size, void* d_ws, size_t ws_size,
                              hipStream_t stream) {
    const float* hm = (const float*)d_in[0];
    int* out = (int*)d_out;
    float* rowv_ws = (float*)d_ws;
    int*   rowc_ws = (int*)((char*)d_ws + (size_t)128 * 512 * sizeof(float));

    phase1_kernel<<<dim3(8, 128), dim3(256), 0, stream>>>(hm, rowv_ws, rowc_ws);
    phase2_kernel<<<dim3(128), dim3(640), 0, stream>>>(hm, rowv_ws, rowc_ws, out);
}